// Round 12
// baseline (324.934 us; speedup 1.0000x reference)
//
#include <hip/hip_runtime.h>

// GRU, fp16 MFMA + fp32 accum, T=512 B=1024 I=H=64.
// Round 12 = R11 (311us best) + dependency-chain surgery:
//  - Accumulators split by operand: x-chains (crx/czx/cnx, bias-seeded,
//    2-deep, hidden under the ds_read-h latency) and SIX INDEPENDENT 1-deep
//    h-MFMAs (crh0/1, czh0/1, cnh0/1). Post-ds-ready MFMA depth: 2 -> 1.
//    Merged with 20 v_add_f32. Evidence: R10 h-only=1515 cyc/step, R11
//    (+only ~45 issue cyc of x-work chained INTO the accs) = 1810: the
//    +295 is dependent-MFMA latency, not issue.
//  - exp2 via __builtin_amdgcn_exp2f (raw v_exp_f32, no ocml wrapper).
//  - Uniform/lane address split for X and out (scalar-engine offsets),
//    running out pointer, literal-parity STEPs.
// No cross-step acc state, no acc copies (R4's failure mode).
// C-layout (verified R3..R11): col(unit)=lane&15, row(batch)=(lane>>4)*4+reg.

typedef _Float16 half8  __attribute__((ext_vector_type(8)));
typedef __fp16   fp16x2 __attribute__((ext_vector_type(2)));
typedef float    f32x4  __attribute__((ext_vector_type(4)));
typedef int      i32x4  __attribute__((ext_vector_type(4)));

#define T_STEPS 512
#define BATCH   1024
#define LOG2E   1.4426950408889634f

struct XBuf { float4 a0, a1, b0, b1; };

__device__ __forceinline__ int pk2(float x, float y) {
    fp16x2 p = __builtin_amdgcn_cvt_pkrtz(x, y);
    return __builtin_bit_cast(int, p);
}

__device__ __forceinline__ half8 cvt8p(const float4& a, const float4& b) {
    i32x4 v;
    v[0] = pk2(a.x, a.y); v[1] = pk2(a.z, a.w);
    v[2] = pk2(b.x, b.y); v[3] = pk2(b.z, b.w);
    return __builtin_bit_cast(half8, v);
}

__device__ __forceinline__ half8 loadw8s(const float* p, float s) {
    const float4* q = (const float4*)p;
    float4 a = q[0], b = q[1];
    half8 h;
    h[0] = (_Float16)(a.x * s); h[1] = (_Float16)(a.y * s);
    h[2] = (_Float16)(a.z * s); h[3] = (_Float16)(a.w * s);
    h[4] = (_Float16)(b.x * s); h[5] = (_Float16)(b.y * s);
    h[6] = (_Float16)(b.z * s); h[7] = (_Float16)(b.w * s);
    return h;
}

__device__ __forceinline__ void block_sync() {
    asm volatile("s_waitcnt lgkmcnt(0)" ::: "memory");
    __builtin_amdgcn_s_barrier();
    asm volatile("" ::: "memory");
}

#define MFMA16(A, B, C) __builtin_amdgcn_mfma_f32_16x16x32_f16((A), (B), (C), 0, 0, 0)

__global__ __launch_bounds__(256, 1)
void gru_fused_kernel(const float* __restrict__ X,     // [T,B,64]
                      const float* __restrict__ W_ih,  // [192,64]
                      const float* __restrict__ W_hh,  // [192,64]
                      const float* __restrict__ b_ih,  // [192]
                      const float* __restrict__ b_hh,  // [192]
                      float* __restrict__ out)         // [T*B*64] ++ [B*64]
{
    const int tid   = threadIdx.x;
    const int wq    = tid >> 6;       // unit group
    const int l     = tid & 63;
    const int c     = l & 15;         // batch row within tile / B-col
    const int g4    = l >> 4;         // lane group
    const int u     = wq * 16 + c;    // hidden-unit column
    const int brow0 = blockIdx.x * 16;

    __shared__ __align__(16) _Float16 hbuf[2][16][72];

    const float sRZ = -LOG2E;
    const float sN  = 2.0f * LOG2E;

    // ---- 12 W B-fragments, fp16, pre-scaled, loaded once (48 VGPR) ----
    const half8 Brx0 = loadw8s(W_ih + (u)       * 64 +      8 * g4, sRZ);
    const half8 Brx1 = loadw8s(W_ih + (u)       * 64 + 32 + 8 * g4, sRZ);
    const half8 Bzx0 = loadw8s(W_ih + (64 + u)  * 64 +      8 * g4, sRZ);
    const half8 Bzx1 = loadw8s(W_ih + (64 + u)  * 64 + 32 + 8 * g4, sRZ);
    const half8 Bnx0 = loadw8s(W_ih + (128 + u) * 64 +      8 * g4, sN);
    const half8 Bnx1 = loadw8s(W_ih + (128 + u) * 64 + 32 + 8 * g4, sN);
    const half8 Brh0 = loadw8s(W_hh + (u)       * 64 +      8 * g4, sRZ);
    const half8 Brh1 = loadw8s(W_hh + (u)       * 64 + 32 + 8 * g4, sRZ);
    const half8 Bzh0 = loadw8s(W_hh + (64 + u)  * 64 +      8 * g4, sRZ);
    const half8 Bzh1 = loadw8s(W_hh + (64 + u)  * 64 + 32 + 8 * g4, sRZ);
    const half8 Bnh0 = loadw8s(W_hh + (128 + u) * 64 +      8 * g4, sN);
    const half8 Bnh1 = loadw8s(W_hh + (128 + u) * 64 + 32 + 8 * g4, sN);

    const float rb  = sRZ * (b_ih[u]      + b_hh[u]);
    const float zb  = sRZ * (b_ih[64 + u] + b_hh[64 + u]);
    const float nxb = sN * b_ih[128 + u];
    const float nhb = sN * b_hh[128 + u];

    const f32x4 rb4  = {rb, rb, rb, rb};
    const f32x4 zb4  = {zb, zb, zb, zb};
    const f32x4 nxb4 = {nxb, nxb, nxb, nxb};
    const f32x4 nhb4 = {nhb, nhb, nhb, nhb};
    const f32x4 z4   = {0.f, 0.f, 0.f, 0.f};

    // ---- uniform/lane address split ----
    const int xlane = (brow0 + c) * 64 + 8 * g4;          // lane part for X
    float* outp = out + (size_t)((brow0 + 4 * g4) * 64 + u);  // running ptr

#define ISSUE_X(XB, TN) do {                                                  \
        const float* px_ = X + (size_t)(TN) * (BATCH * 64) + xlane;           \
        const float4* q_ = (const float4*)px_;                                \
        (XB).a0 = q_[0]; (XB).a1 = q_[1];                                     \
        (XB).b0 = q_[8]; (XB).b1 = q_[9];                                     \
    } while (0)

    XBuf xb0, xb1;
    ISSUE_X(xb0, 0);
    ISSUE_X(xb1, 1);

    // zero h(0) buffers
    for (int k = tid; k < 2 * 16 * 72; k += 256)
        ((_Float16*)hbuf)[k] = (_Float16)0.f;
    __syncthreads();

    f32x4 hp = {0.f, 0.f, 0.f, 0.f};

    // STEP: P is a LITERAL parity; T is the current step (uniform).
#define STEP(T, P, XA) do {                                                   \
        /* h reads issue first; latency covered by x-work below */            \
        const half8 hf0 = *(const half8*)&hbuf[P][c][8 * g4];                 \
        const half8 hf1 = *(const half8*)&hbuf[P][c][32 + 8 * g4];            \
        const half8 xf0 = cvt8p((XA).a0, (XA).a1);                            \
        const half8 xf1 = cvt8p((XA).b0, (XA).b1);                            \
        { int tn_ = (T) + 2; if (tn_ > T_STEPS - 1) tn_ = T_STEPS - 1;        \
          ISSUE_X(XA, tn_); }                                                 \
        /* x-chains: 2-deep, register-fed, hidden under ds_read latency */    \
        f32x4 crx = MFMA16(xf0, Brx0, rb4);  crx = MFMA16(xf1, Brx1, crx);    \
        f32x4 czx = MFMA16(xf0, Bzx0, zb4);  czx = MFMA16(xf1, Bzx1, czx);    \
        f32x4 cnx = MFMA16(xf0, Bnx0, nxb4); cnx = MFMA16(xf1, Bnx1, cnx);    \
        /* h-side: SIX INDEPENDENT 1-deep MFMAs (post-ds-ready depth = 1) */  \
        const f32x4 crh0 = MFMA16(hf0, Brh0, z4);                             \
        const f32x4 crh1 = MFMA16(hf1, Brh1, z4);                             \
        const f32x4 czh0 = MFMA16(hf0, Bzh0, z4);                             \
        const f32x4 czh1 = MFMA16(hf1, Bzh1, z4);                             \
        const f32x4 cnh0 = MFMA16(hf0, Bnh0, nhb4);                           \
        const f32x4 cnh1 = MFMA16(hf1, Bnh1, z4);                             \
        _Pragma("unroll")                                                     \
        for (int i = 0; i < 4; ++i) {                                         \
            const float cr  = (crx[i] + crh0[i]) + crh1[i];                   \
            const float cz  = (czx[i] + czh0[i]) + czh1[i];                   \
            const float cnh = cnh0[i] + cnh1[i];                              \
            const float rv = __builtin_amdgcn_rcpf(                           \
                                 1.f + __builtin_amdgcn_exp2f(cr));           \
            const float zv = __builtin_amdgcn_rcpf(                           \
                                 1.f + __builtin_amdgcn_exp2f(cz));           \
            const float npre = fmaf(rv, cnh, cnx[i]);                         \
            const float e  = __builtin_amdgcn_exp2f(npre);                    \
            const float nv = 1.f - 2.f * __builtin_amdgcn_rcpf(e + 1.f);      \
            const float hn = fmaf(zv, hp[i] - nv, nv);                        \
            hp[i] = hn;                                                       \
            hbuf[(P) ^ 1][4 * g4 + i][u] = (_Float16)hn;                      \
            outp[i * 64] = hn;                                                \
        }                                                                     \
        outp += BATCH * 64;                                                   \
        block_sync();                                                         \
    } while (0)

    #pragma unroll 1
    for (int t = 0; t < T_STEPS; t += 2) {
        STEP(t,     0, xb0);
        STEP(t + 1, 1, xb1);
    }

    // h_last: outp now points at the T_STEPS*BATCH*64 tail + lane offset
    #pragma unroll
    for (int i = 0; i < 4; ++i)
        outp[i * 64] = hp[i];

#undef STEP
#undef ISSUE_X
}

extern "C" void kernel_launch(void* const* d_in, const int* in_sizes, int n_in,
                              void* d_out, int out_size, void* d_ws, size_t ws_size,
                              hipStream_t stream) {
    const float* X    = (const float*)d_in[0];
    const float* W_ih = (const float*)d_in[1];
    const float* W_hh = (const float*)d_in[2];
    const float* b_ih = (const float*)d_in[3];
    const float* b_hh = (const float*)d_in[4];
    float* out = (float*)d_out;

    gru_fused_kernel<<<dim3(BATCH / 16), dim3(256), 0, stream>>>(
        X, W_ih, W_hh, b_ih, b_hh, out);
}